// Round 6
// baseline (104.107 us; speedup 1.0000x reference)
//
#include <hip/hip_runtime.h>
#include <hip/hip_bf16.h>
#include <math.h>

constexpr int NCAPS = 1152;
constexpr int CIN   = 8;
constexpr int COUT  = 16;
constexpr int BATCH = 128;
constexpr int DCAPS = 10;

// ---------------- Kernel A: u = einsum('bni,dnio->dbno'), bf16 out ----------
// Block = (d, 64-row n-chunk, 32-wide b-quarter); 256 thr. All 64 lanes of a
// wave share one b: x-loads are 512 B fully contiguous (16 rows x 32 B, each
// broadcast to 4 oq lanes) and u-stores are 512 B fully contiguous. Each
// thread's w quad (8 x float4, 32 VGPR) is loaded once and reused for 32 b's.
__global__ __launch_bounds__(256, 1) void u_kernel(
    const float* __restrict__ x,          // [128, 1152, 8]
    const float* __restrict__ w,          // [10, 1152, 8, 16]
    __hip_bfloat16* __restrict__ u)       // [10, 128, 1152, 16] bf16
{
    const int i  = blockIdx.x;            // 720 blocks
    const int bq = i & 3;
    const int nc = (i >> 2) % 18;
    const int d  = (i >> 2) / 18;

    const int t  = threadIdx.x;
    const int oq = t & 3;
    const int nl = (t >> 2) & 15;
    const int wv = t >> 6;
    const int n  = nc * 64 + wv * 16 + nl;
    const int b0 = bq * 32;

    const float* wr = w + ((size_t)(d * NCAPS + n)) * (CIN * COUT) + oq * 4;
    float4 W[CIN];
    #pragma unroll
    for (int ii = 0; ii < CIN; ++ii)
        W[ii] = *(const float4*)(wr + ii * COUT);

    const float* xp = x + ((size_t)b0 * NCAPS + n) * CIN;
    __hip_bfloat16* up =
        u + ((size_t)(d * BATCH + b0) * NCAPS + n) * COUT + oq * 4;

    #pragma unroll 4
    for (int bi = 0; bi < 32; ++bi) {
        const float4* xr = (const float4*)(xp + (size_t)bi * NCAPS * CIN);
        float4 xa = xr[0], xc = xr[1];
        float xs[CIN] = {xa.x, xa.y, xa.z, xa.w, xc.x, xc.y, xc.z, xc.w};
        float4 acc = {0.f, 0.f, 0.f, 0.f};
        #pragma unroll
        for (int ii = 0; ii < CIN; ++ii) {
            acc.x = fmaf(xs[ii], W[ii].x, acc.x);
            acc.y = fmaf(xs[ii], W[ii].y, acc.y);
            acc.z = fmaf(xs[ii], W[ii].z, acc.z);
            acc.w = fmaf(xs[ii], W[ii].w, acc.w);
        }
        union { unsigned short us[4]; uint2 v; } pk;
        pk.us[0] = __bfloat16_as_ushort(__float2bfloat16(acc.x));
        pk.us[1] = __bfloat16_as_ushort(__float2bfloat16(acc.y));
        pk.us[2] = __bfloat16_as_ushort(__float2bfloat16(acc.z));
        pk.us[3] = __bfloat16_as_ushort(__float2bfloat16(acc.w));
        *(uint2*)(up + (size_t)bi * NCAPS * COUT) = pk.v;
    }
}

// ---------------- Kernel B: routing over precomputed u ----------------------
// Block = (d,b), 512 threads (8 waves). u slice (36.8 KB bf16) read fully
// contiguously (512 B per wave-instr), expanded to f32 regs (9 float4/thr),
// then 3 routing iterations in registers with xor-shuffle reductions.
constexpr int BNT    = 512;
constexpr int BWAVES = BNT / 64;
constexpr int QPT    = NCAPS * 4 / BNT;   // 9 o-quads per thread

__global__ __launch_bounds__(BNT, 1) void routing_kernel(
    const __hip_bfloat16* __restrict__ u, // [10, 128, 1152, 16] bf16
    float* __restrict__ out)              // [10, 128, 16]
{
    __shared__ float4 red[BWAVES][4];
    __shared__ float  sbuf[BWAVES];
    __shared__ float  zbuf[BWAVES];
    __shared__ float4 vsh[4];

    const int i = blockIdx.x;
    const int d = i >> 7;
    const int b = i & 127;

    const int t    = threadIdx.x;
    const int wave = t >> 6;
    const int lane = t & 63;
    const int oq   = t & 3;
    const int r    = t >> 2;              // 0..127

    const __hip_bfloat16* up =
        u + ((size_t)(d * BATCH + b) * NCAPS) * COUT + oq * 4;

    float4 u4[QPT];
    #pragma unroll
    for (int j = 0; j < QPT; ++j) {
        const int n = j * 128 + r;
        uint2 pv = *(const uint2*)(up + (size_t)n * COUT);
        float4 uf;
        uf.x = __uint_as_float(pv.x << 16);
        uf.y = __uint_as_float(pv.x & 0xffff0000u);
        uf.z = __uint_as_float(pv.y << 16);
        uf.w = __uint_as_float(pv.y & 0xffff0000u);
        u4[j] = uf;
    }

    float bb[QPT];
    #pragma unroll
    for (int j = 0; j < QPT; ++j) bb[j] = 0.f;

    #pragma unroll
    for (int it = 0; it < 3; ++it) {
        float4 p = {0.f, 0.f, 0.f, 0.f};
        float z = 0.f;
        if (it == 0) {
            #pragma unroll
            for (int j = 0; j < QPT; ++j) {
                p.x += u4[j].x; p.y += u4[j].y;
                p.z += u4[j].z; p.w += u4[j].w;
            }
        } else {
            float m = bb[0];
            #pragma unroll
            for (int j = 1; j < QPT; ++j) m = fmaxf(m, bb[j]);
            #pragma unroll
            for (int off = 1; off < 64; off <<= 1)
                m = fmaxf(m, __shfl_xor(m, off));
            if (lane == 0) sbuf[wave] = m;
            __syncthreads();
            float M = sbuf[0];
            #pragma unroll
            for (int wv = 1; wv < BWAVES; ++wv) M = fmaxf(M, sbuf[wv]);
            #pragma unroll
            for (int j = 0; j < QPT; ++j) {
                float e = __expf(bb[j] - M);
                z += e;
                p.x = fmaf(e, u4[j].x, p.x);
                p.y = fmaf(e, u4[j].y, p.y);
                p.z = fmaf(e, u4[j].z, p.z);
                p.w = fmaf(e, u4[j].w, p.w);
            }
            z += __shfl_xor(z, 1);
            z += __shfl_xor(z, 2);
        }
        #pragma unroll
        for (int off = 4; off < 64; off <<= 1) {
            p.x += __shfl_xor(p.x, off);
            p.y += __shfl_xor(p.y, off);
            p.z += __shfl_xor(p.z, off);
            p.w += __shfl_xor(p.w, off);
            if (it != 0) z += __shfl_xor(z, off);
        }
        if (lane < 4) red[wave][oq] = p;          // lanes 0..3 hold the result
        if (it != 0 && lane == 0) zbuf[wave] = z;
        __syncthreads();

        if (t < 4) {   // t == oq: combine waves, squash, publish
            float4 s = red[0][t];
            #pragma unroll
            for (int wv = 1; wv < BWAVES; ++wv) {
                float4 rr = red[wv][t];
                s.x += rr.x; s.y += rr.y; s.z += rr.z; s.w += rr.w;
            }
            float scale;
            if (it == 0) {
                scale = 1.f / (float)NCAPS;
            } else {
                float Z = zbuf[0];
                #pragma unroll
                for (int wv = 1; wv < BWAVES; ++wv) Z += zbuf[wv];
                scale = 4.f / Z;   // each n replicated on 4 oq lanes
            }
            s.x *= scale; s.y *= scale; s.z *= scale; s.w *= scale;
            float4 v;
            v.x = s.x * fabsf(s.x) / (1.f + s.x * s.x);
            v.y = s.y * fabsf(s.y) / (1.f + s.y * s.y);
            v.z = s.z * fabsf(s.z) / (1.f + s.z * s.z);
            v.w = s.w * fabsf(s.w) / (1.f + s.w * s.w);
            vsh[t] = v;
            if (it == 2)
                ((float4*)(out + ((size_t)d * BATCH + b) * COUT))[t] = v;
        }
        __syncthreads();

        if (it < 2) {
            float4 v = vsh[oq];
            #pragma unroll
            for (int j = 0; j < QPT; ++j) {
                float dotv = u4[j].x * v.x + u4[j].y * v.y +
                             u4[j].z * v.z + u4[j].w * v.w;
                dotv += __shfl_xor(dotv, 1);
                dotv += __shfl_xor(dotv, 2);
                bb[j] += dotv;
            }
        }
    }
}

extern "C" void kernel_launch(void* const* d_in, const int* in_sizes, int n_in,
                              void* d_out, int out_size, void* d_ws, size_t ws_size,
                              hipStream_t stream) {
    const float* x = (const float*)d_in[0];
    const float* w = (const float*)d_in[1];
    float* out = (float*)d_out;
    __hip_bfloat16* u = (__hip_bfloat16*)d_ws;   // 10*128*1152*16*2 B = 47 MB

    u_kernel<<<DCAPS * 18 * 4, 256, 0, stream>>>(x, w, u);
    routing_kernel<<<DCAPS * BATCH, BNT, 0, stream>>>(u, out);
}

// Round 7
// 87.066 us; speedup vs baseline: 1.1957x; 1.1957x over previous
//
#include <hip/hip_runtime.h>
#include <hip/hip_bf16.h>
#include <math.h>

constexpr int NCAPS = 1152;
constexpr int CIN   = 8;
constexpr int COUT  = 16;
constexpr int BATCH = 128;
constexpr int DCAPS = 10;

// ---------------- Kernel A: u = einsum('bni,dnio->dbno'), bf16 out ----------
// R5 version (measured best; R6's 720-block remap regressed -10 us from lost
// occupancy). Block = (d, 16-row n-chunk, 64-wide b-half); 1440 blocks.
// Thread = (oq, bgrp, nl): w quad (8 x float4) loaded once, reused for 16 b's.
__global__ __launch_bounds__(256, 1) void u_kernel(
    const float* __restrict__ x,          // [128, 1152, 8]
    const float* __restrict__ w,          // [10, 1152, 8, 16]
    __hip_bfloat16* __restrict__ u)       // [10, 128, 1152, 16] bf16
{
    const int i  = blockIdx.x;
    const int bh = i & 1;                 // b-half
    const int nc = (i >> 1) % 72;         // n-chunk (16 rows)
    const int d  = (i >> 1) / 72;

    const int t    = threadIdx.x;
    const int oq   = t & 3;
    const int bgrp = (t >> 2) & 3;
    const int nl   = t >> 4;              // 0..15
    const int n    = nc * 16 + nl;
    const int b0   = bh * 64 + bgrp * 16;

    const float* wr = w + ((size_t)(d * NCAPS + n)) * (CIN * COUT) + oq * 4;
    float4 W[CIN];
    #pragma unroll
    for (int ii = 0; ii < CIN; ++ii)
        W[ii] = *(const float4*)(wr + ii * COUT);

    const float* xp = x + ((size_t)b0 * NCAPS + n) * CIN;
    __hip_bfloat16* up = u + ((size_t)(d * BATCH + b0) * NCAPS + n) * COUT + oq * 4;

    #pragma unroll
    for (int bi = 0; bi < 16; ++bi) {
        const float4* xr = (const float4*)(xp + (size_t)bi * NCAPS * CIN);
        float4 xa = xr[0], xc = xr[1];
        float xs[CIN] = {xa.x, xa.y, xa.z, xa.w, xc.x, xc.y, xc.z, xc.w};
        float4 acc = {0.f, 0.f, 0.f, 0.f};
        #pragma unroll
        for (int ii = 0; ii < CIN; ++ii) {
            acc.x = fmaf(xs[ii], W[ii].x, acc.x);
            acc.y = fmaf(xs[ii], W[ii].y, acc.y);
            acc.z = fmaf(xs[ii], W[ii].z, acc.z);
            acc.w = fmaf(xs[ii], W[ii].w, acc.w);
        }
        union { unsigned short us[4]; uint2 v; } pk;
        pk.us[0] = __bfloat16_as_ushort(__float2bfloat16(acc.x));
        pk.us[1] = __bfloat16_as_ushort(__float2bfloat16(acc.y));
        pk.us[2] = __bfloat16_as_ushort(__float2bfloat16(acc.z));
        pk.us[3] = __bfloat16_as_ushort(__float2bfloat16(acc.w));
        *(uint2*)(up + (size_t)bi * NCAPS * COUT) = pk.v;
    }
}

// ---------------- Kernel B: routing over precomputed u ----------------------
// Block = (d,b), 256 threads (4 waves): 5 blocks/CU -> exactly 1280 blocks in
// one occupancy pass (zero tail; the R5 8-wave version had a 1.67-pass tail).
// Thread owns 9 half-rows kept PACKED bf16 (9 x uint4 = 1 KB/wave load instr),
// unpacked on use. Softmax uses a constant shift (exp(b-20)) instead of a
// block max: shift-invariance makes it exact, deleting one shuffle-tree +
// barrier per iteration. Logits |b| <~ 40 after 2 updates -> no overflow.
constexpr int BNT  = 256;
constexpr int BWAV = BNT / 64;
constexpr int JPT  = 9;               // half-rows per thread: 1152*2/256

__device__ __forceinline__ void unpack8(const uint4 pv, float* f) {
    f[0] = __uint_as_float(pv.x << 16);
    f[1] = __uint_as_float(pv.x & 0xffff0000u);
    f[2] = __uint_as_float(pv.y << 16);
    f[3] = __uint_as_float(pv.y & 0xffff0000u);
    f[4] = __uint_as_float(pv.z << 16);
    f[5] = __uint_as_float(pv.z & 0xffff0000u);
    f[6] = __uint_as_float(pv.w << 16);
    f[7] = __uint_as_float(pv.w & 0xffff0000u);
}

__global__ __launch_bounds__(BNT, 1) void routing_kernel(
    const __hip_bfloat16* __restrict__ u, // [10, 128, 1152, 16] bf16
    float* __restrict__ out)              // [10, 128, 16]
{
    __shared__ float red[BWAV][COUT];     // per-wave partial s
    __shared__ float zred[BWAV];          // per-wave exp-sum
    __shared__ float vsh[COUT];           // squashed v

    const int i = blockIdx.x;
    const int d = i >> 7;
    const int b = i & 127;

    const int t    = threadIdx.x;
    const int wave = t >> 6;
    const int lane = t & 63;
    const int oh   = t & 1;               // o-half: 0 -> o 0..7, 1 -> o 8..15
    const int r    = t >> 1;              // 0..127

    const __hip_bfloat16* up =
        u + ((size_t)(d * BATCH + b) * NCAPS) * COUT + oh * 8;

    uint4 upk[JPT];
    #pragma unroll
    for (int j = 0; j < JPT; ++j)
        upk[j] = *(const uint4*)(up + (size_t)(j * 128 + r) * COUT);

    float bb[JPT];
    #pragma unroll
    for (int j = 0; j < JPT; ++j) bb[j] = 0.f;

    #pragma unroll
    for (int it = 0; it < 3; ++it) {
        float p8[8] = {0.f,0.f,0.f,0.f,0.f,0.f,0.f,0.f};
        float z = 0.f;
        if (it == 0) {
            #pragma unroll
            for (int j = 0; j < JPT; ++j) {
                float uf[8]; unpack8(upk[j], uf);
                #pragma unroll
                for (int k = 0; k < 8; ++k) p8[k] += uf[k];
            }
        } else {
            #pragma unroll
            for (int j = 0; j < JPT; ++j) {
                float e = __expf(bb[j] - 20.f);   // constant-shift softmax
                z += e;
                float uf[8]; unpack8(upk[j], uf);
                #pragma unroll
                for (int k = 0; k < 8; ++k) p8[k] = fmaf(e, uf[k], p8[k]);
            }
        }
        // reduce over the wave's 32 r-lanes (lane bits 1..5). After this,
        // lane 0 (oh=0) and lane 1 (oh=1) hold the wave sums for their o's;
        // z on lane {0,1} counts each n exactly once.
        #pragma unroll
        for (int off = 2; off < 64; off <<= 1) {
            #pragma unroll
            for (int k = 0; k < 8; ++k) p8[k] += __shfl_xor(p8[k], off);
            if (it != 0) z += __shfl_xor(z, off);
        }
        if (lane < 2) {
            #pragma unroll
            for (int k = 0; k < 8; ++k) red[wave][oh * 8 + k] = p8[k];
            if (it != 0 && lane == 0) zred[wave] = z;
        }
        __syncthreads();

        if (t < COUT) {   // t == o: combine waves, squash, publish
            float s = red[0][t];
            #pragma unroll
            for (int wv = 1; wv < BWAV; ++wv) s += red[wv][t];
            float scale;
            if (it == 0) {
                scale = 1.f / (float)NCAPS;
            } else {
                float Z = zred[0];
                #pragma unroll
                for (int wv = 1; wv < BWAV; ++wv) Z += zred[wv];
                scale = 1.f / Z;
            }
            s *= scale;
            float v = s * fabsf(s) / (1.f + s * s);
            vsh[t] = v;
            if (it == 2)
                out[((size_t)d * BATCH + b) * COUT + t] = v;
        }
        __syncthreads();

        if (it < 2) {
            float vloc[8];
            #pragma unroll
            for (int k = 0; k < 8; ++k) vloc[k] = vsh[oh * 8 + k];
            #pragma unroll
            for (int j = 0; j < JPT; ++j) {
                float uf[8]; unpack8(upk[j], uf);
                float dv = 0.f;
                #pragma unroll
                for (int k = 0; k < 8; ++k) dv = fmaf(uf[k], vloc[k], dv);
                dv += __shfl_xor(dv, 1);   // add the other o-half
                bb[j] += dv;
            }
            __syncthreads();   // vsh/red reused next iteration
        }
    }
}

extern "C" void kernel_launch(void* const* d_in, const int* in_sizes, int n_in,
                              void* d_out, int out_size, void* d_ws, size_t ws_size,
                              hipStream_t stream) {
    const float* x = (const float*)d_in[0];
    const float* w = (const float*)d_in[1];
    float* out = (float*)d_out;
    __hip_bfloat16* u = (__hip_bfloat16*)d_ws;   // 10*128*1152*16*2 B = 47 MB

    u_kernel<<<DCAPS * 72 * 2, 256, 0, stream>>>(x, w, u);
    routing_kernel<<<DCAPS * BATCH, BNT, 0, stream>>>(u, out);
}